// Round 1
// baseline (500.353 us; speedup 1.0000x reference)
//
#include <hip/hip_runtime.h>

// out accumulator = d_out itself (zeroed first), then finalized in place.
// grad[i] = (2/N) * nf[i] * ( sum_{e:row=i} (zr[i]-zr[col_e]) + sum_{e:col=i} (zr[i]-zr[row_e]) )
// with zr[j] = nf[j]*z[j].  out = z - COEFF*grad.

__global__ void edge_scatter_kernel(const float* __restrict__ z,
                                    const int* __restrict__ ei,   // [2*E]: row = ei[e], col = ei[E+e]
                                    const float* __restrict__ nf, // [N]
                                    float* __restrict__ acc,      // [N*D], pre-zeroed
                                    int E, int D, long total) {
    long idx = (long)blockIdx.x * blockDim.x + threadIdx.x;
    if (idx >= total) return;
    int e = (int)(idx / D);
    int d = (int)(idx - (long)e * D);
    int r = ei[e];
    int c = ei[E + e];
    float zr = nf[r] * z[(long)r * D + d];
    float zc = nf[c] * z[(long)c * D + d];
    float diff = zr - zc;
    atomicAdd(&acc[(long)r * D + d],  diff);
    atomicAdd(&acc[(long)c * D + d], -diff);
}

__global__ void finalize_kernel(const float* __restrict__ z,
                                const float* __restrict__ nf, // [N]
                                float* __restrict__ out,      // [N*D], holds accumulator on entry
                                float scale, int D, long total) {
    long i = (long)blockIdx.x * blockDim.x + threadIdx.x;
    if (i >= total) return;
    int node = (int)(i / D);
    out[i] = z[i] - scale * nf[node] * out[i];
}

extern "C" void kernel_launch(void* const* d_in, const int* in_sizes, int n_in,
                              void* d_out, int out_size, void* d_ws, size_t ws_size,
                              hipStream_t stream) {
    const float* z  = (const float*)d_in[0];
    // d_in[1] = x, unused in the 'Lap' branch
    const int*   ei = (const int*)d_in[2];
    const float* nf = (const float*)d_in[3];
    float* out = (float*)d_out;

    const int ND = in_sizes[0];        // N*D
    const int Nn = in_sizes[3];        // N  (norm_factor is [N,1])
    const int D  = ND / Nn;            // 48
    const int E  = in_sizes[2] / 2;    // 1.6M

    const float scale = 0.1f * 2.0f / (float)Nn;  // COEFF * 2 / N

    // Zero the accumulator (d_out doubles as accumulator).
    hipMemsetAsync(out, 0, (size_t)ND * sizeof(float), stream);

    const int block = 256;
    const long totalE = (long)E * D;
    const int gridE = (int)((totalE + block - 1) / block);
    edge_scatter_kernel<<<gridE, block, 0, stream>>>(z, ei, nf, out, E, D, totalE);

    const long totalN = (long)ND;
    const int gridN = (int)((totalN + block - 1) / block);
    finalize_kernel<<<gridN, block, 0, stream>>>(z, nf, out, scale, D, totalN);
}